// Round 1
// baseline (394.223 us; speedup 1.0000x reference)
//
#include <hip/hip_runtime.h>

// CostVolume2D: out[b, d+48, h, w] = (1/64) * sum_c l[b,c,h,w] * r[b,c,h,w-d]
// B=4, C=64, H=256, W=512, 97 planes.  Band of G = L^T R per (b,h) via bf16 MFMA.
// R3: half-row blocks (512 thr, 8 waves) -> 76 KiB LDS -> TWO resident blocks
// per CU with independent barriers, so one block's staging overlaps another's
// compute/epilogue (R2 had 1 block/CU: all phases serialized, 32% HBM).
// R halo (48 cols each side) is staged zero-filled, removing the boundary
// branch in the MFMA loop; halo re-reads are L2/L3 hits.

#define B_  4
#define C_  64
#define H_  256
#define W_  512
#define ND  97
#define HW  (H_ * W_)

#define WBLK 256        // half-row per block
#define RCOL 352        // staged R columns (48-halo + 256 + 48-halo)
#define PADH 257        // out-chunk row stride (256+1) -> conflict-free scatter
#define CH0  49         // planes in chunk 0 (chunk 1 = 48)

typedef __attribute__((ext_vector_type(8))) short  short8;
typedef __attribute__((ext_vector_type(4))) float  floatx4;

__device__ __forceinline__ unsigned f2bf(float f) {
    unsigned u = __builtin_bit_cast(unsigned, f);
    return (u + 0x7FFFu + ((u >> 16) & 1u)) >> 16;   // RNE fp32->bf16
}

// Fragment-linear bf16 layout: 16B chunk = (tile*8 + (c>>3))*16 + (col&15),
// element = c&7.  One ds_read_b128 per MFMA fragment.
union SM {
    struct {
        short l[WBLK * C_];   // 32 KiB: 16 w-tiles
        short r[RCOL * C_];   // 44 KiB: 22 u-tiles (u = w0-48 .. w0+303)
    } st;
    float out_s[CH0 * PADH];  // 50.4 KiB (aliased after compute)
};

__global__ __launch_bounds__(512, 4) void cost_volume_kernel(
    const float* __restrict__ L, const float* __restrict__ R,
    float* __restrict__ out)
{
    __shared__ SM sm;
    const int tid  = threadIdx.x;
    const int half = blockIdx.x;     // 0..1
    const int h    = blockIdx.y;
    const int b    = blockIdx.z;
    const int w0   = half << 8;
    const size_t in_base = (((size_t)b * C_) * H_ + h) * (size_t)W_;

    // ---- stage L (256 cols, x 1/64 folded in) + aligned middle of R ----
    {
        const int wl = tid & 255;          // local col
        const int ch = tid >> 8;           // 0..1
        const int m  = wl & 15, wq = wl >> 4;
        const float* lp = L + in_base + w0 + wl;
        const float* rp = R + in_base + w0 + wl;   // u = w0+wl -> ul = 48+wl
        #pragma unroll
        for (int i = 0; i < 4; ++i) {
            const int cc = ch + 2 * i;     // c-chunk 0..7 across (ch,i)
            unsigned dl[4], dr[4];
            #pragma unroll
            for (int jj = 0; jj < 4; ++jj) {
                float l0 = lp[(size_t)(cc * 8 + 2 * jj)     * HW] * 0.015625f;
                float l1 = lp[(size_t)(cc * 8 + 2 * jj + 1) * HW] * 0.015625f;
                float r0 = rp[(size_t)(cc * 8 + 2 * jj)     * HW];
                float r1 = rp[(size_t)(cc * 8 + 2 * jj + 1) * HW];
                dl[jj] = f2bf(l0) | (f2bf(l1) << 16);
                dr[jj] = f2bf(r0) | (f2bf(r1) << 16);
            }
            const int lchunk = ( wq      * 8 + cc) * 16 + m;
            const int rchunk = ((wq + 3) * 8 + cc) * 16 + m;   // ul = 48+wl
            *((uint4*)&sm.st.l[lchunk * 8]) = make_uint4(dl[0], dl[1], dl[2], dl[3]);
            *((uint4*)&sm.st.r[rchunk * 8]) = make_uint4(dr[0], dr[1], dr[2], dr[3]);
        }
    }
    // ---- stage R halo: ul 0..47 and 304..351, zero-filled out of range ----
    if (tid < 192) {
        const int ch = tid & 1;
        const int hl = tid >> 1;                   // 0..95
        const int ul = (hl < 48) ? hl : hl + 256;  // 0..47 | 304..351
        const int u  = w0 - 48 + ul;
        const bool valid = (unsigned)u < (unsigned)W_;
        const int m = ul & 15, uq = ul >> 4;
        const float* rp = R + in_base + (valid ? u : 0);   // safe addr
        #pragma unroll
        for (int i = 0; i < 4; ++i) {
            const int cc = ch + 2 * i;
            unsigned dr[4];
            #pragma unroll
            for (int jj = 0; jj < 4; ++jj) {
                float r0 = rp[(size_t)(cc * 8 + 2 * jj)     * HW];
                float r1 = rp[(size_t)(cc * 8 + 2 * jj + 1) * HW];
                r0 = valid ? r0 : 0.f;
                r1 = valid ? r1 : 0.f;
                dr[jj] = f2bf(r0) | (f2bf(r1) << 16);
            }
            const int rchunk = (uq * 8 + cc) * 16 + m;
            *((uint4*)&sm.st.r[rchunk * 8]) = make_uint4(dr[0], dr[1], dr[2], dr[3]);
        }
    }
    __syncthreads();

    // ---- banded GEMM: wave wv owns local w-tiles wv and wv+8 ----
    // local u-tile for (lt, t) is lt + t  (global u-tile = wt + t - 3);
    // halo zero-fill makes all 7 t's valid -> no branch.
    const int lane = tid & 63;
    const int wv   = tid >> 6;          // 0..7
    const int q    = lane >> 4, m16 = lane & 15;
    const short8* lv = (const short8*)sm.st.l;
    const short8* rv = (const short8*)sm.st.r;

    floatx4 acc[2][7];
    #pragma unroll
    for (int hf = 0; hf < 2; ++hf) {
        const int lt = wv + 8 * hf;
        const short8 a0 = lv[(lt * 8 +     q) * 16 + m16];
        const short8 a1 = lv[(lt * 8 + 4 + q) * 16 + m16];
        #pragma unroll
        for (int t = 0; t < 7; ++t) {
            const int ut = lt + t;      // 0..21, always staged
            floatx4 c = {0.f, 0.f, 0.f, 0.f};
            const short8 b0 = rv[(ut * 8 +     q) * 16 + m16];
            const short8 b1 = rv[(ut * 8 + 4 + q) * 16 + m16];
            c = __builtin_amdgcn_mfma_f32_16x16x32_bf16(a0, b0, c, 0, 0, 0);
            c = __builtin_amdgcn_mfma_f32_16x16x32_bf16(a1, b1, c, 0, 0, 0);
            acc[hf][t] = c;
        }
    }

    // ---- epilogue: two d-chunks through aliased LDS, coalesced stores ----
    // C/D layout: col(u)=lane&15, row(w)=(lane>>4)*4+reg; d_idx = d+48.
    float* ob = out + (((size_t)b * ND) * H_ + h) * (size_t)W_ + w0;
    int lo = 0;
    #pragma unroll
    for (int ck = 0; ck < 2; ++ck) {
        const int cnt = ck ? (ND - CH0) : CH0;
        __syncthreads();    // staging reads (ck=0) / prev chunk reads (ck=1) done
        #pragma unroll
        for (int hf = 0; hf < 2; ++hf) {
            const int lt = wv + 8 * hf;
            #pragma unroll
            for (int t = 0; t < 7; ++t) {
                #pragma unroll
                for (int r = 0; r < 4; ++r) {
                    const int ml    = q * 4 + r;
                    const int d_idx = ml - m16 + 96 - 16 * t;
                    const int drel  = d_idx - lo;
                    if ((unsigned)drel < (unsigned)cnt)
                        sm.out_s[drel * PADH + lt * 16 + ml] = acc[hf][t][r];
                }
            }
        }
        __syncthreads();
        for (int i = tid; i < cnt * WBLK; i += 512) {
            const int pr = i >> 8, w = i & 255;
            ob[(size_t)(lo + pr) * HW + w] = sm.out_s[pr * PADH + w];
        }
        lo += CH0;
    }
}

extern "C" void kernel_launch(void* const* d_in, const int* in_sizes, int n_in,
                              void* d_out, int out_size, void* d_ws, size_t ws_size,
                              hipStream_t stream) {
    const float* L = (const float*)d_in[0];
    const float* R = (const float*)d_in[1];
    float* out = (float*)d_out;
    (void)in_sizes; (void)n_in; (void)d_ws; (void)ws_size; (void)out_size;
    dim3 grid(2, H_, B_);   // two half-row blocks per (b,h)
    hipLaunchKernelGGL(cost_volume_kernel, grid, dim3(512), 0, stream, L, R, out);
}

// Round 3
// 389.504 us; speedup vs baseline: 1.0121x; 1.0121x over previous
//
#include <hip/hip_runtime.h>

// CostVolume2D: out[b, d+48, h, w] = (1/64) * sum_c l[b,c,h,w] * r[b,c,h,w-d]
// B=4, C=64, H=256, W=512, 97 planes.  Band of G = L^T R per (b,h) via bf16 MFMA.
// R5 == R4 resubmitted (R4 bench died infra-side: container failed twice,
// push times were 1000x normal; kernel audit found no hang/race/spill path).
// Design: persistent half-row blocks (256 blocks = 1/CU, 512 thr, 8 rows
// each) with cross-row software pipelining.  out_s is NOT aliased over the
// stage buffers (125 KiB total LDS), so row k+1's global loads are issued
// into registers right after row k's MFMAs, fly under the epilogue, and
// commit to LDS after the last store.  Row k's stores drain under row
// k+1's compute.  (R3's two-blocks/CU ran in lockstep: no overlap, 136 us.)

#define B_  4
#define C_  64
#define H_  256
#define W_  512
#define ND  97
#define HW  (H_ * W_)

#define WBLK 256        // half-row per block
#define RCOL 352        // staged R columns (48 halo + 256 + 48 halo)
#define PADH 257        // out_s row stride -> conflict-free scatter + reads
#define CH0  49         // planes in chunk 0 (chunk 1 = 48)
#define NBLK 256        // persistent blocks (1 per CU)
#define NROW 8          // half-rows per block: 4*256*2 / 256

typedef __attribute__((ext_vector_type(8))) short  short8;
typedef __attribute__((ext_vector_type(4))) float  floatx4;

__device__ __forceinline__ unsigned f2bf(float f) {
    unsigned u = __builtin_bit_cast(unsigned, f);
    return (u + 0x7FFFu + ((u >> 16) & 1u)) >> 16;   // RNE fp32->bf16
}

// Fragment-linear bf16 layout: 16B chunk = (tile*8 + (c>>3))*16 + (col&15),
// element = c&7.  One ds_read_b128 per MFMA fragment, conflict-free.
struct SM {
    short l[WBLK * C_];      // 32 KiB: 16 w-tiles
    short r[RCOL * C_];      // 44 KiB: 22 u-tiles (u = w0-48 .. w0+303)
    float out_s[CH0 * PADH]; // 49.2 KiB (separate -> cross-row pipelining)
};

__global__ __launch_bounds__(512, 2) void cost_volume_kernel(
    const float* __restrict__ L, const float* __restrict__ R,
    float* __restrict__ out)
{
    __shared__ SM sm;
    const int tid  = threadIdx.x;
    const int bid  = blockIdx.x;
    const int half = bid & 1;           // constant per block
    const int hb   = bid >> 1;          // 0..127
    const int w0   = half << 8;

    // ---- staging geometry (constant per thread) ----
    const int wl = tid & 255;           // local col
    const int ch = tid >> 8;            // 0..1
    const int m  = wl & 15, wq = wl >> 4;

    const bool hhalo = tid < 384;       // halo: 96 cols x 64 ch over 384 thr
    const int hcol = tid % 96;          // 0..95
    const int hch  = tid / 96;          // 0..3 -> channels hch*16 .. +15
    const int hul  = (hcol < 48) ? hcol : hcol + 256;
    const int hu   = w0 - 48 + hul;
    const bool hvalid = hhalo && ((unsigned)hu < (unsigned)W_);

    float Lf[32], Rf[32], Hf[16];       // prefetch registers for one row

    auto issue = [&](int k) {           // issue global loads for row k
        const int b = k >> 1;
        const int h = hb + ((k & 1) << 7);
        const size_t base = ((size_t)b * C_ * H_ + h) * (size_t)W_;
        const float* lp = L + base + w0 + wl;
        const float* rp = R + base + w0 + wl;
        #pragma unroll
        for (int i = 0; i < 4; ++i) {
            const int cc = ch + 2 * i;
            #pragma unroll
            for (int jj = 0; jj < 8; ++jj) {
                Lf[i * 8 + jj] = lp[(size_t)(cc * 8 + jj) * HW];
                Rf[i * 8 + jj] = rp[(size_t)(cc * 8 + jj) * HW];
            }
        }
        if (hhalo) {
            const float* hp = R + base + (hvalid ? hu : (w0 + wl));  // safe
            #pragma unroll
            for (int kk = 0; kk < 16; ++kk)
                Hf[kk] = hp[(size_t)(hch * 16 + kk) * HW];
        }
    };

    auto commit = [&]() {               // convert + write LDS stage buffers
        #pragma unroll
        for (int i = 0; i < 4; ++i) {
            const int cc = ch + 2 * i;
            unsigned dl[4], dr[4];
            #pragma unroll
            for (int jj = 0; jj < 4; ++jj) {
                dl[jj] = f2bf(Lf[i * 8 + 2 * jj]     * 0.015625f)
                       | (f2bf(Lf[i * 8 + 2 * jj + 1] * 0.015625f) << 16);
                dr[jj] = f2bf(Rf[i * 8 + 2 * jj])
                       | (f2bf(Rf[i * 8 + 2 * jj + 1]) << 16);
            }
            *((uint4*)&sm.l[(( wq      * 8 + cc) * 16 + m) * 8]) =
                make_uint4(dl[0], dl[1], dl[2], dl[3]);
            *((uint4*)&sm.r[(((wq + 3) * 8 + cc) * 16 + m) * 8]) =
                make_uint4(dr[0], dr[1], dr[2], dr[3]);
        }
        if (hhalo) {
            const int hm = hul & 15, huq = hul >> 4;
            #pragma unroll
            for (int t2 = 0; t2 < 2; ++t2) {
                const int cc = 2 * hch + t2;
                unsigned dr[4];
                #pragma unroll
                for (int jj = 0; jj < 4; ++jj) {
                    float r0 = hvalid ? Hf[t2 * 8 + 2 * jj]     : 0.f;
                    float r1 = hvalid ? Hf[t2 * 8 + 2 * jj + 1] : 0.f;
                    dr[jj] = f2bf(r0) | (f2bf(r1) << 16);
                }
                *((uint4*)&sm.r[((huq * 8 + cc) * 16 + hm) * 8]) =
                    make_uint4(dr[0], dr[1], dr[2], dr[3]);
            }
        }
    };

    const int lane = tid & 63;
    const int wv   = tid >> 6;          // 0..7
    const int q    = lane >> 4, m16 = lane & 15;
    const short8* lv = (const short8*)sm.l;
    const short8* rv = (const short8*)sm.r;

    issue(0);
    commit();
    __syncthreads();

    for (int k = 0; k < NROW; ++k) {
        const int b = k >> 1;
        const int h = hb + ((k & 1) << 7);
        float* ob = out + ((size_t)b * ND * H_ + h) * (size_t)W_ + w0;

        // ---- banded GEMM: wave wv owns local w-tiles wv, wv+8 ----
        floatx4 acc[2][7];
        #pragma unroll
        for (int hf = 0; hf < 2; ++hf) {
            const int lt = wv + 8 * hf;
            const short8 a0 = lv[(lt * 8 +     q) * 16 + m16];
            const short8 a1 = lv[(lt * 8 + 4 + q) * 16 + m16];
            #pragma unroll
            for (int t = 0; t < 7; ++t) {
                const int ut = lt + t;        // 0..21, halo zero-filled
                floatx4 c = {0.f, 0.f, 0.f, 0.f};
                const short8 b0 = rv[(ut * 8 +     q) * 16 + m16];
                const short8 b1 = rv[(ut * 8 + 4 + q) * 16 + m16];
                c = __builtin_amdgcn_mfma_f32_16x16x32_bf16(a0, b0, c, 0, 0, 0);
                c = __builtin_amdgcn_mfma_f32_16x16x32_bf16(a1, b1, c, 0, 0, 0);
                acc[hf][t] = c;
            }
        }

        // prefetch next row: loads fly under the epilogue below
        if (k + 1 < NROW) issue(k + 1);

        // ---- epilogue: two d-chunks through out_s, coalesced stores ----
        // C/D layout: col(u)=lane&15, row(w)=(lane>>4)*4+reg; d_idx = d+48.
        int lo = 0;
        #pragma unroll
        for (int ck = 0; ck < 2; ++ck) {
            const int cnt = ck ? (ND - CH0) : CH0;
            if (ck) __syncthreads();          // chunk-0 out_s reads done
            #pragma unroll
            for (int hf = 0; hf < 2; ++hf) {
                const int lt = wv + 8 * hf;
                #pragma unroll
                for (int t = 0; t < 7; ++t) {
                    #pragma unroll
                    for (int r = 0; r < 4; ++r) {
                        const int ml    = q * 4 + r;
                        const int d_idx = ml - m16 + 96 - 16 * t;
                        const int drel  = d_idx - lo;
                        if ((unsigned)drel < (unsigned)cnt)
                            sm.out_s[drel * PADH + lt * 16 + ml] = acc[hf][t][r];
                    }
                }
            }
            __syncthreads();                  // scatter done
            for (int i = tid; i < cnt * WBLK; i += 512) {
                const int pr = i >> 8, w = i & 255;
                ob[(size_t)(lo + pr) * HW + w] = sm.out_s[pr * PADH + w];
            }
            lo += CH0;
        }

        // commit next row's stage while this row's stores drain
        if (k + 1 < NROW) commit();
        __syncthreads();    // stage ready + chunk-1 out_s reads done
    }
}

extern "C" void kernel_launch(void* const* d_in, const int* in_sizes, int n_in,
                              void* d_out, int out_size, void* d_ws, size_t ws_size,
                              hipStream_t stream) {
    const float* L = (const float*)d_in[0];
    const float* R = (const float*)d_in[1];
    float* out = (float*)d_out;
    (void)in_sizes; (void)n_in; (void)d_ws; (void)ws_size; (void)out_size;
    dim3 grid(NBLK);    // persistent: one block per CU, 8 half-rows each
    hipLaunchKernelGGL(cost_volume_kernel, grid, dim3(512), 0, stream, L, R, out);
}